// Round 14
// baseline (113.428 us; speedup 1.0000x reference)
//
#include <hip/hip_runtime.h>
#include <hip/hip_bf16.h>
#include <stdint.h>
#include <math.h>

#define B_ 2
#define T_ 2048
#define DIM_ 1024
#define H_ 16
#define HD_ 64
#define NROWS_ (B_*T_)
#define NQKV 1152
#define UNITS_PER_BH 80   // sum_{qt=0}^{31} ceil((qt+1)/8)
#define NUNITS (16 * UNITS_PER_BH)
// Q pre-scale folded into projection epilogue: scores come out as t = s*0.125*log2e
#define CT_SCALE 0.18033688f
// softcap in t-domain: 50*tanh(s/400)*log2e = t + C2*t^3 + C4*t^5 (|t|<=11.6)
#define C2_ (-6.40603e-5f)
#define C4_ (4.92447e-9f)

typedef __bf16 bf16_t;
typedef __attribute__((ext_vector_type(8))) __bf16 bf16x8;
typedef __attribute__((ext_vector_type(4))) __bf16 bf16x4;
typedef __attribute__((ext_vector_type(4))) float f32x4;
typedef __attribute__((ext_vector_type(16))) float f32x16;

// cumulative chunk count: cb(qt) = sum_{m=1}^{qt} ceil(m/8)
__device__ __forceinline__ int cb(int q) {
  int a = q >> 3, r = q & 7;
  return 4 * a * (a + 1) + r * (a + 1);
}

// Swizzled LDS byte address for [rows][64] bf16 tiles (128B rows):
// byte = row*128 + ((col*2) ^ ((row&7)<<4)).
__device__ __forceinline__ bf16_t* swz(bf16_t* base, int row, int col) {
  return (bf16_t*)((char*)base + (row << 7) + (((col << 1) ^ ((row & 7) << 4))));
}

__device__ __forceinline__ f32x16 mfma32(bf16x8 a, bf16x8 b, f32x16 c) {
  return __builtin_amdgcn_mfma_f32_32x32x16_bf16(a, b, c, 0, 0, 0);
}

__device__ __forceinline__ unsigned cvt_pk(float lo, float hi) {
  unsigned r;
  asm("v_cvt_pk_bf16_f32 %0, %1, %2" : "=v"(r) : "v"(lo), "v"(hi));
  return r;
}
__device__ __forceinline__ void plswap(unsigned& x, unsigned& y) {
  asm volatile("v_permlane32_swap_b32 %0, %1" : "+v"(x), "+v"(y));
}

#define GLOAD(SRC, DST)                                                        \
  __builtin_amdgcn_global_load_lds(                                            \
      (const __attribute__((address_space(1))) unsigned int*)(uintptr_t)(SRC), \
      (__attribute__((address_space(3))) unsigned int*)(uintptr_t)(DST), 16, 0, 0)

// ---------------- single fused f32 -> bf16 conversion ----------------
#define C_S0 (NROWS_*DIM_/8)
#define C_S1 (C_S0 + DIM_*DIM_/8)
#define C_S2 (C_S1 + HD_*DIM_/8)
#define C_S3 (C_S2 + HD_*DIM_/8)
#define C_S4 (C_S3 + DIM_*DIM_/8)
__global__ __launch_bounds__(256) void cvt_all(
    const float* __restrict__ x, const float* __restrict__ wq,
    const float* __restrict__ wk, const float* __restrict__ wv,
    const float* __restrict__ wo, bf16_t* __restrict__ xb,
    bf16_t* __restrict__ wqkvb, bf16_t* __restrict__ wob) {
  int i = blockIdx.x * 256 + threadIdx.x;
  if (i >= C_S4) return;
  const float* src; bf16_t* dst; int j;
  if (i < C_S0)      { src = x;  dst = xb; j = i; }
  else if (i < C_S1) { src = wq; dst = wqkvb; j = i - C_S0; }
  else if (i < C_S2) { src = wk; dst = wqkvb + (size_t)DIM_ * DIM_; j = i - C_S1; }
  else if (i < C_S3) { src = wv; dst = wqkvb + (size_t)(DIM_ + HD_) * DIM_; j = i - C_S2; }
  else               { src = wo; dst = wob; j = i - C_S3; }
  float4 a = ((const float4*)src)[2 * (size_t)j];
  float4 b = ((const float4*)src)[2 * (size_t)j + 1];
  bf16x8 o;
  o[0] = (bf16_t)a.x; o[1] = (bf16_t)a.y; o[2] = (bf16_t)a.z; o[3] = (bf16_t)a.w;
  o[4] = (bf16_t)b.x; o[5] = (bf16_t)b.y; o[6] = (bf16_t)b.z; o[7] = (bf16_t)b.w;
  *(bf16x8*)(dst + 8 * (size_t)j) = o;
}

// ---------------- bf16 MFMA GEMM, C[m][n] = sum_k A[m][k]*Bw[n][k] ----------------
// 128x128 tile, BK=64, 512 threads / 8 waves (2 row-halves x 4 col-quarters).
// One global_load_lds round stages a full 128x32 half-tile (LDS linear:
// lane offset 16*l bytes == row=tid>>2, slot=tid&3; swizzle on global src).
// QKV mode: col-tile spans 2 heads (wn-pairs) ->
//   q/k heads: fused RMSNorm + RoPE epilogue (q additionally * CT_SCALE)
//   v head (col-tile 8, wn>=2): written TRANSPOSED to vt[d][row].
template<int OUTF32, int QKV>
__global__ __launch_bounds__(512) void gemm_bt(const bf16_t* __restrict__ A,
    const bf16_t* __restrict__ Bw, void* __restrict__ Cv,
    bf16_t* __restrict__ vt, const float* __restrict__ qg,
    const float* __restrict__ kgm, const float* __restrict__ fc,
    const float* __restrict__ fs, int N, int K) {
  __shared__ bf16_t As[2][128 * 32];
  __shared__ bf16_t Bs[2][128 * 32];
  __shared__ float RowS[128][4];
  const int tid = threadIdx.x;
  const int w = tid >> 6, lane = tid & 63;
  const int row0 = blockIdx.x * 128, col0 = blockIdx.y * 128;
  const int wm = w >> 2, wn = w & 3;
  const int rr = lane & 15, kg = lane >> 4;
  f32x4 acc[4][2];
#pragma unroll
  for (int i = 0; i < 4; ++i)
#pragma unroll
    for (int j = 0; j < 2; ++j) acc[i][j] = (f32x4){0.f, 0.f, 0.f, 0.f};
  const int srow = tid >> 2;                      // 512 thr -> 128 rows x 4 slots
  const int skoff = ((tid & 3) ^ (srow & 3)) << 3;
  const bf16_t* gA = A + (size_t)(row0 + srow) * K + skoff;
  const bf16_t* gB = Bw + (size_t)(col0 + srow) * K + skoff;
  bf16_t* dA = As[0] + (size_t)w * 512;           // = linear lane*16B dst
  bf16_t* dB = Bs[0] + (size_t)w * 512;
  for (int kt = 0; kt < K; kt += 64) {
    __syncthreads();
#pragma unroll
    for (int kk = 0; kk < 2; ++kk) {
      GLOAD(gA + kt + 32 * kk, dA + kk * 4096);
      GLOAD(gB + kt + 32 * kk, dB + kk * 4096);
    }
    __syncthreads();
#pragma unroll
    for (int kk = 0; kk < 2; ++kk) {
      bf16x8 af[4], bfv[2];
#pragma unroll
      for (int mi = 0; mi < 4; ++mi) {
        int r = 64 * wm + 16 * mi + rr;
        af[mi] = *(const bf16x8*)(&As[kk][r * 32 + ((kg ^ (r & 3)) << 3)]);
      }
#pragma unroll
      for (int ni = 0; ni < 2; ++ni) {
        int r = 32 * wn + 16 * ni + rr;
        bfv[ni] = *(const bf16x8*)(&Bs[kk][r * 32 + ((kg ^ (r & 3)) << 3)]);
      }
#pragma unroll
      for (int mi = 0; mi < 4; ++mi)
#pragma unroll
        for (int ni = 0; ni < 2; ++ni)
          acc[mi][ni] = __builtin_amdgcn_mfma_f32_16x16x32_bf16(af[mi], bfv[ni],
                                                                acc[mi][ni], 0, 0, 0);
    }
  }
  const int crow = (lane >> 4) * 4, ccol = lane & 15;
  if (QKV) {
    const int colbase = col0 + 64 * (wn >> 1);    // head base (wn-pair)
    const bool is_v = (colbase == DIM_ + HD_);
    // phase 1: all non-V waves publish their 32-col per-row sumsq
    if (!is_v) {
#pragma unroll
      for (int mi = 0; mi < 4; ++mi)
#pragma unroll
        for (int r = 0; r < 4; ++r) {
          float ss = acc[mi][0][r] * acc[mi][0][r] + acc[mi][1][r] * acc[mi][1][r];
          ss += __shfl_xor(ss, 1, 64);
          ss += __shfl_xor(ss, 2, 64);
          ss += __shfl_xor(ss, 4, 64);
          ss += __shfl_xor(ss, 8, 64);
          if (ccol == 0) RowS[64 * wm + 16 * mi + crow + r][wn] = ss;
        }
    }
    __syncthreads();
    if (is_v) {
      // V head -> transposed store vt[d][row]
#pragma unroll
      for (int mi = 0; mi < 4; ++mi)
#pragma unroll
        for (int ni = 0; ni < 2; ++ni) {
          int d = 32 * (wn & 1) + 16 * ni + ccol;
          size_t rg = (size_t)(row0 + 64 * wm + 16 * mi + crow);
          bf16x4 pk;
#pragma unroll
          for (int r = 0; r < 4; ++r) pk[r] = (bf16_t)acc[mi][ni][r];
          *(bf16x4*)(vt + (size_t)d * NROWS_ + rg) = pk;
        }
    } else {
      const float* gam = (colbase < DIM_) ? qg : kgm;
      const float qs = (colbase < DIM_) ? CT_SCALE : 1.f;
      const float g0 = gam[32 * (wn & 1) + ccol];
      const float g1 = gam[32 * (wn & 1) + 16 + ccol];
      const int sbase = wn & 2;
#pragma unroll
      for (int mi = 0; mi < 4; ++mi)
#pragma unroll
        for (int r = 0; r < 4; ++r) {
          const int row = 64 * wm + 16 * mi + crow + r;
          const int t = (row0 + row) & (T_ - 1);
          const float rms = rsqrtf(
              (RowS[row][sbase] + RowS[row][sbase + 1]) * (1.f / HD_) + 1e-6f);
#pragma unroll
          for (int ni = 0; ni < 2; ++ni) {
            const int colh = 32 * (wn & 1) + 16 * ni + ccol;  // col within head
            float val = acc[mi][ni][r] * rms * (ni ? g1 : g0);
            float partner = __shfl_xor(val, 1, 64);
            float c = fc[t * (HD_ / 2) + (colh >> 1)];
            float s = fs[t * (HD_ / 2) + (colh >> 1)];
            float res = ((ccol & 1) == 0) ? (val * c - partner * s)
                                          : (partner * s + val * c);
            ((bf16_t*)Cv)[(size_t)(row0 + row) * N + colbase + colh] =
                (bf16_t)(res * qs);
          }
        }
    }
  } else {
#pragma unroll
    for (int mi = 0; mi < 4; ++mi)
#pragma unroll
      for (int ni = 0; ni < 2; ++ni)
#pragma unroll
        for (int r = 0; r < 4; ++r) {
          size_t rg = (size_t)(row0 + 64 * wm + 16 * mi + crow + r);
          size_t cg = (size_t)(col0 + 32 * wn + 16 * ni + ccol);
          if (OUTF32) ((float*)Cv)[rg * N + cg] = acc[mi][ni][r];
          else        ((bf16_t*)Cv)[rg * N + cg] = (bf16_t)acc[mi][ni][r];
        }
  }
}

// ---------------- attn part 1: uniform split-K flash units (r13, unchanged) ----------------
__global__ __launch_bounds__(512, 4) void attn_part(const bf16_t* __restrict__ qkv,
                                                    const bf16_t* __restrict__ vt,
                                                    bf16_t* __restrict__ partO,
                                                    float* __restrict__ partL,
                                                    bf16_t* __restrict__ att) {
  __shared__ __align__(16) char SMEM[32768];
  __shared__ float Lx[4][32];
  __shared__ float Lf[4][32];
  bf16_t* Ks = (bf16_t*)SMEM;            // [2][64*64] (kslice pair)
  bf16_t* Vt = (bf16_t*)(SMEM + 16384);  // [2][64*64] transposed [d][t]
  const int tid = threadIdx.x;
  const int w = tid >> 6, lane = tid & 63;
  // ---- decode unit (heavy chunks first) ----
  const int u = NUNITS - 1 - (int)blockIdx.x;
  const int bh = u / UNITS_PER_BH;          // b*8 + head-pair
  const int rem = u - bh * UNITS_PER_BH;
  const int b = bh >> 3, hp = bh & 7;
  int qt = 0;
  while (qt < 31 && cb(qt + 1) <= rem) ++qt;
  const int chunk = rem - cb(qt);
  const int nt = min(8, qt + 1 - chunk * 8);   // tiles in this chunk (1..8)
  const int NP = (nt + 1) >> 1;                // pair-steps
  const int qt0 = qt * 64;
  const int h0 = hp * 2;
  const size_t bT = (size_t)b * T_;
  const int lo = lane & 31, hi = lane >> 5;
  const int hw = w >> 2, qg = (w >> 1) & 1, ks = w & 1, g2 = w >> 1;

  bf16x8 qf[4];
  {
    const bf16_t* qbase =
        qkv + (bT + qt0 + 32 * qg + lo) * NQKV + (h0 + hw) * HD_ + hi * 8;
#pragma unroll
    for (int s = 0; s < 4; ++s) qf[s] = *(const bf16x8*)(qbase + 16 * s);
  }
  const int srow = tid >> 3, scol = (tid & 7) * 8;
  const bf16_t* kp = qkv + (bT + chunk * 512 + srow) * NQKV + DIM_ + scol;
  const bf16_t* vtp = vt + (size_t)srow * NROWS_ + bT + chunk * 512 + scol;
  uint4 kpre0, kpre1, vpre0, vpre1;

#define PREFETCH() do {                                                       \
    kpre0 = *(const uint4*)kp;                                                \
    kpre1 = *(const uint4*)(kp + (size_t)64 * NQKV);                          \
    vpre0 = *(const uint4*)vtp;                                               \
    vpre1 = *(const uint4*)(vtp + 64);                                        \
    kp += (size_t)128 * NQKV;                                                 \
    vtp += 128;                                                               \
  } while (0)
#define STAGE() do {                                                          \
    *(uint4*)swz(Ks, srow, scol) = kpre0;                                     \
    *(uint4*)swz(Ks + 4096, srow, scol) = kpre1;                              \
    *(uint4*)swz(Vt, srow, scol) = vpre0;                                     \
    *(uint4*)swz(Vt + 4096, srow, scol) = vpre1;                              \
  } while (0)

  f32x16 accO0 = {}, accO1 = {};
  float l_ = 0.f;
  bf16_t* KsP = Ks + ks * 4096;
  bf16_t* VtP = Vt + ks * 4096;

  PREFETCH();
  STAGE();
  if (NP > 1) PREFETCH();
  __syncthreads();

  for (int j = 0; j < NP; ++j) {
    const int ctl = 2 * j + ks;
    if (ctl < nt) {
      const int ct = chunk * 8 + ctl;   // global 64-key tile index
      f32x16 S0 = {}, S1 = {};
      __builtin_amdgcn_s_setprio(1);
#pragma unroll
      for (int s = 0; s < 4; ++s) {
        bf16x8 kf0 = *(const bf16x8*)swz(KsP, lo, 16 * s + hi * 8);
        bf16x8 kf1 = *(const bf16x8*)swz(KsP, 32 + lo, 16 * s + hi * 8);
        S0 = mfma32(kf0, qf[s], S0);
        S1 = mfma32(kf1, qf[s], S1);
      }
      __builtin_amdgcn_s_setprio(0);
      const bool full = (64 * ct + 63 <= qt0 + 32 * qg);
      const int qrel = qt0 + 32 * qg + lo - 64 * ct;
      float psum = 0.f;
#pragma unroll
      for (int kh = 0; kh < 2; ++kh)
#pragma unroll
        for (int r = 0; r < 16; ++r) {
          float t = (kh == 0) ? S0[r] : S1[r];
          float t2 = t * t;
          float ww = fmaf(t2, C4_, C2_);
          float pv = exp2f(fmaf(t * t2, ww, t));
          if (!full) {
            int koff = 32 * kh + (r & 3) + 8 * (r >> 2) + 4 * hi;
            pv = (koff <= qrel) ? pv : 0.f;
          }
          psum += pv;
          if (kh == 0) S0[r] = pv; else S1[r] = pv;
        }
      psum += __shfl_xor(psum, 32, 64);
      l_ += psum;
      __builtin_amdgcn_s_setprio(1);
#pragma unroll
      for (int s = 0; s < 4; ++s) {
        const int base = (s & 1) * 8;
        float p0, p1, p2, p3, p4, p5, p6, p7;
        if (s >> 1) {
          p0 = S1[base + 0]; p1 = S1[base + 1]; p2 = S1[base + 2]; p3 = S1[base + 3];
          p4 = S1[base + 4]; p5 = S1[base + 5]; p6 = S1[base + 6]; p7 = S1[base + 7];
        } else {
          p0 = S0[base + 0]; p1 = S0[base + 1]; p2 = S0[base + 2]; p3 = S0[base + 3];
          p4 = S0[base + 4]; p5 = S0[base + 5]; p6 = S0[base + 6]; p7 = S0[base + 7];
        }
        unsigned a0 = cvt_pk(p0, p1), a1 = cvt_pk(p2, p3);
        unsigned b0 = cvt_pk(p4, p5), b1 = cvt_pk(p6, p7);
        plswap(a0, b0);
        plswap(a1, b1);
        union { unsigned uu[4]; bf16x8 v; } pa;
        pa.uu[0] = a0; pa.uu[1] = a1; pa.uu[2] = b0; pa.uu[3] = b1;
        bf16x8 vf0 = *(const bf16x8*)swz(VtP, lo, 16 * s + hi * 8);
        bf16x8 vf1 = *(const bf16x8*)swz(VtP, 32 + lo, 16 * s + hi * 8);
        accO0 = mfma32(pa.v, vf0, accO0);
        accO1 = mfma32(pa.v, vf1, accO1);
      }
      __builtin_amdgcn_s_setprio(0);
    }
    __syncthreads();
    if (j + 1 < NP) {
      STAGE();
      if (j + 2 < NP) PREFETCH();
      __syncthreads();
    }
  }
#undef PREFETCH
#undef STAGE

  // merge kslices in LDS (reuse K/V space); ks=0 writes output/partials
  float* exch = (float*)SMEM;
  float* my = exch + ((size_t)g2 * 64 + lane) * 32;
  if (ks == 1) {
#pragma unroll
    for (int qd = 0; qd < 4; ++qd) {
      int sl = (qd ^ (lane & 7)) * 4;
      f32x4 t0 = {accO0[4*qd], accO0[4*qd+1], accO0[4*qd+2], accO0[4*qd+3]};
      *(f32x4*)(my + sl) = t0;
      int sl2 = ((qd + 4) ^ (lane & 7)) * 4;
      f32x4 t1 = {accO1[4*qd], accO1[4*qd+1], accO1[4*qd+2], accO1[4*qd+3]};
      *(f32x4*)(my + sl2) = t1;
    }
    if (hi == 0) Lx[g2][lo] = l_;
  }
  __syncthreads();
  if (ks == 0) {
#pragma unroll
    for (int qd = 0; qd < 4; ++qd) {
      int sl = (qd ^ (lane & 7)) * 4;
      f32x4 t0 = *(const f32x4*)(my + sl);
      accO0[4*qd] += t0[0]; accO0[4*qd+1] += t0[1];
      accO0[4*qd+2] += t0[2]; accO0[4*qd+3] += t0[3];
      int sl2 = ((qd + 4) ^ (lane & 7)) * 4;
      f32x4 t1 = *(const f32x4*)(my + sl2);
      accO1[4*qd] += t1[0]; accO1[4*qd+1] += t1[1];
      accO1[4*qd+2] += t1[2]; accO1[4*qd+3] += t1[3];
    }
    float l_tot = l_ + Lx[g2][lo];
    if (qt < 8) {
      if (hi == 0) Lf[g2][lo] = l_tot;
#pragma unroll
      for (int rq = 0; rq < 4; ++rq) {
        f32x4 lv = *(const f32x4*)&Lf[g2][8 * rq + 4 * hi];
#pragma unroll
        for (int c = 0; c < 4; ++c) {
          size_t grow = bT + qt0 + 32 * qg + 8 * rq + 4 * hi + c;
          float linv = 1.f / lv[c];
          att[grow * DIM_ + (h0 + hw) * HD_ + lo] =
              (bf16_t)(accO0[4 * rq + c] * linv);
          att[grow * DIM_ + (h0 + hw) * HD_ + 32 + lo] =
              (bf16_t)(accO1[4 * rq + c] * linv);
        }
      }
    } else {
      bf16_t* po = partO + ((size_t)u * 2 + hw) * 4096;
#pragma unroll
      for (int rq = 0; rq < 4; ++rq)
#pragma unroll
        for (int c = 0; c < 4; ++c) {
          int q = 32 * qg + 8 * rq + 4 * hi + c;
          po[q * 64 + lo] = (bf16_t)accO0[4 * rq + c];
          po[q * 64 + 32 + lo] = (bf16_t)accO1[4 * rq + c];
        }
      if (hi == 0) partL[((size_t)u * 2 + hw) * 64 + 32 * qg + lo] = l_tot;
    }
  }
}

// ---------------- attn part 2: merge partials (qt >= 8 only) ----------------
__global__ __launch_bounds__(256) void attn_reduce(const bf16_t* __restrict__ partO,
                                                   const float* __restrict__ partL,
                                                   bf16_t* __restrict__ att) {
  const int qt = blockIdx.x + 8, h = blockIdx.y, b = blockIdx.z;
  const int nch = (qt + 8) >> 3;
  const size_t ubase = (size_t)(b * 8 + (h >> 1)) * UNITS_PER_BH + cb(qt);
  const int hw = h & 1;
  const int tid = threadIdx.x;
  const int q = tid >> 2, dblk = (tid & 3) * 16;
  f32x4 o[4] = {};
  float l = 0.f;
  for (int c = 0; c < nch; ++c) {
    const bf16_t* po = partO + ((ubase + c) * 2 + hw) * 4096 + q * 64 + dblk;
    bf16x8 v0 = *(const bf16x8*)po;
    bf16x8 v1 = *(const bf16x8*)(po + 8);
#pragma unroll
    for (int i = 0; i < 4; ++i) o[0][i] += (float)v0[i];
#pragma unroll
    for (int i = 0; i < 4; ++i) o[1][i] += (float)v0[4 + i];
#pragma unroll
    for (int i = 0; i < 4; ++i) o[2][i] += (float)v1[i];
#pragma unroll
    for (int i = 0; i < 4; ++i) o[3][i] += (float)v1[4 + i];
    l += partL[((ubase + c) * 2 + hw) * 64 + q];
  }
  const float linv = 1.f / l;
  bf16_t* dst = att + ((size_t)(b * T_ + qt * 64 + q)) * DIM_ + h * HD_ + dblk;
  bf16x8 r0, r1;
#pragma unroll
  for (int i = 0; i < 4; ++i) { r0[i] = (bf16_t)(o[0][i] * linv);
                                r0[4+i] = (bf16_t)(o[1][i] * linv);
                                r1[i] = (bf16_t)(o[2][i] * linv);
                                r1[4+i] = (bf16_t)(o[3][i] * linv); }
  *(bf16x8*)dst = r0;
  *(bf16x8*)(dst + 8) = r1;
}

extern "C" void kernel_launch(void* const* d_in, const int* in_sizes, int n_in,
                              void* d_out, int out_size, void* d_ws, size_t ws_size,
                              hipStream_t stream) {
  const float* x   = (const float*)d_in[0];
  const float* wq  = (const float*)d_in[1];
  const float* wk  = (const float*)d_in[2];
  const float* wv  = (const float*)d_in[3];
  const float* wo  = (const float*)d_in[4];
  const float* qg  = (const float*)d_in[5];
  const float* kgm = (const float*)d_in[6];
  const float* fc  = (const float*)d_in[7];
  const float* fs  = (const float*)d_in[8];
  float* out = (float*)d_out;

  bf16_t* xb    = (bf16_t*)d_ws;
  bf16_t* wqkvb = xb + (size_t)NROWS_ * DIM_;
  bf16_t* wob   = wqkvb + (size_t)NQKV * DIM_;
  bf16_t* qkvo  = wob + (size_t)DIM_ * DIM_;
  bf16_t* attb  = qkvo + (size_t)NROWS_ * NQKV;
  bf16_t* partO = attb + (size_t)NROWS_ * DIM_;                 // NUNITS*2*4096 bf16
  float*  partL = (float*)(partO + (size_t)NUNITS * 2 * 4096);  // NUNITS*2*64 f32
  bf16_t* vtb   = (bf16_t*)(partL + (size_t)NUNITS * 2 * 64);   // HD_ x NROWS_ bf16

  cvt_all<<<(C_S4 + 255) / 256, 256, 0, stream>>>(x, wq, wk, wv, wo, xb, wqkvb, wob);
  gemm_bt<0, 1><<<dim3(NROWS_ / 128, NQKV / 128), 512, 0, stream>>>(
      xb, wqkvb, qkvo, vtb, qg, kgm, fc, fs, NQKV, DIM_);
  attn_part<<<NUNITS, 512, 0, stream>>>(qkvo, vtb, partO, partL, attb);
  attn_reduce<<<dim3(24, H_, B_), 256, 0, stream>>>(partO, partL, attb);
  gemm_bt<1, 0><<<dim3(NROWS_ / 128, DIM_ / 128), 512, 0, stream>>>(
      attb, wob, out, nullptr, nullptr, nullptr, nullptr, nullptr, DIM_, DIM_);
}

// Round 15
// 110.267 us; speedup vs baseline: 1.0287x; 1.0287x over previous
//
#include <hip/hip_runtime.h>
#include <hip/hip_bf16.h>
#include <stdint.h>
#include <math.h>

#define B_ 2
#define T_ 2048
#define DIM_ 1024
#define H_ 16
#define HD_ 64
#define NROWS_ (B_*T_)
#define NQKV 1152
#define UNITS_PER_BH 80   // sum_{qt=0}^{31} ceil((qt+1)/8)
#define NUNITS (16 * UNITS_PER_BH)
// Q pre-scale folded into projection epilogue: scores come out as t = s*0.125*log2e
#define CT_SCALE 0.18033688f
// softcap in t-domain: 50*tanh(s/400)*log2e ~= t + C2*t^3 (|t|<=11.6; C4 term <2e-4)
#define C2_ (-6.40603e-5f)

typedef __bf16 bf16_t;
typedef __attribute__((ext_vector_type(8))) __bf16 bf16x8;
typedef __attribute__((ext_vector_type(4))) __bf16 bf16x4;
typedef __attribute__((ext_vector_type(4))) float f32x4;
typedef __attribute__((ext_vector_type(16))) float f32x16;

// cumulative chunk count: cb(qt) = sum_{m=1}^{qt} ceil(m/8)
__device__ __forceinline__ int cb(int q) {
  int a = q >> 3, r = q & 7;
  return 4 * a * (a + 1) + r * (a + 1);
}

// Swizzled LDS byte address for [rows][64] bf16 tiles (128B rows):
// byte = row*128 + ((col*2) ^ ((row&7)<<4)).
__device__ __forceinline__ bf16_t* swz(bf16_t* base, int row, int col) {
  return (bf16_t*)((char*)base + (row << 7) + (((col << 1) ^ ((row & 7) << 4))));
}

__device__ __forceinline__ f32x16 mfma32(bf16x8 a, bf16x8 b, f32x16 c) {
  return __builtin_amdgcn_mfma_f32_32x32x16_bf16(a, b, c, 0, 0, 0);
}

__device__ __forceinline__ unsigned cvt_pk(float lo, float hi) {
  unsigned r;
  asm("v_cvt_pk_bf16_f32 %0, %1, %2" : "=v"(r) : "v"(lo), "v"(hi));
  return r;
}
__device__ __forceinline__ void plswap(unsigned& x, unsigned& y) {
  asm volatile("v_permlane32_swap_b32 %0, %1" : "+v"(x), "+v"(y));
}

// ---------------- single fused f32 -> bf16 conversion ----------------
#define C_S0 (NROWS_*DIM_/8)
#define C_S1 (C_S0 + DIM_*DIM_/8)
#define C_S2 (C_S1 + HD_*DIM_/8)
#define C_S3 (C_S2 + HD_*DIM_/8)
#define C_S4 (C_S3 + DIM_*DIM_/8)
__global__ __launch_bounds__(256) void cvt_all(
    const float* __restrict__ x, const float* __restrict__ wq,
    const float* __restrict__ wk, const float* __restrict__ wv,
    const float* __restrict__ wo, bf16_t* __restrict__ xb,
    bf16_t* __restrict__ wqkvb, bf16_t* __restrict__ wob) {
  int i = blockIdx.x * 256 + threadIdx.x;
  if (i >= C_S4) return;
  const float* src; bf16_t* dst; int j;
  if (i < C_S0)      { src = x;  dst = xb; j = i; }
  else if (i < C_S1) { src = wq; dst = wqkvb; j = i - C_S0; }
  else if (i < C_S2) { src = wk; dst = wqkvb + (size_t)DIM_ * DIM_; j = i - C_S1; }
  else if (i < C_S3) { src = wv; dst = wqkvb + (size_t)(DIM_ + HD_) * DIM_; j = i - C_S2; }
  else               { src = wo; dst = wob; j = i - C_S3; }
  float4 a = ((const float4*)src)[2 * (size_t)j];
  float4 b = ((const float4*)src)[2 * (size_t)j + 1];
  bf16x8 o;
  o[0] = (bf16_t)a.x; o[1] = (bf16_t)a.y; o[2] = (bf16_t)a.z; o[3] = (bf16_t)a.w;
  o[4] = (bf16_t)b.x; o[5] = (bf16_t)b.y; o[6] = (bf16_t)b.z; o[7] = (bf16_t)b.w;
  *(bf16x8*)(dst + 8 * (size_t)j) = o;
}

// ---------------- bf16 MFMA GEMM (r13-proven), C[m][n] = sum_k A[m][k]*Bw[n][k] ----------------
// 128x64 tile, BK=64, 256 threads. QKV mode: col-tile = one full head ->
//   q/k heads: fused RMSNorm + RoPE epilogue (q additionally * CT_SCALE)
//   v head: written TRANSPOSED to vt[d][row].
template<int OUTF32, int QKV>
__global__ __launch_bounds__(256) void gemm_bt(const bf16_t* __restrict__ A,
    const bf16_t* __restrict__ Bw, void* __restrict__ Cv,
    bf16_t* __restrict__ vt, const float* __restrict__ qg,
    const float* __restrict__ kgm, const float* __restrict__ fc,
    const float* __restrict__ fs, int N, int K) {
  __shared__ bf16_t As[2][128 * 32];
  __shared__ bf16_t Bs[2][64 * 32];
  __shared__ float RowS[128][2];
  const int tid = threadIdx.x;
  const int w = tid >> 6, lane = tid & 63;
  const int row0 = blockIdx.x * 128, col0 = blockIdx.y * 64;
  const int wm = w >> 1, wn = w & 1;
  const int rr = lane & 15, kg = lane >> 4;
  f32x4 acc[4][2];
#pragma unroll
  for (int i = 0; i < 4; ++i)
#pragma unroll
    for (int j = 0; j < 2; ++j) acc[i][j] = (f32x4){0.f, 0.f, 0.f, 0.f};
  const int srow = lane >> 2;
  const int skoff = ((lane & 3) ^ (srow & 3)) << 3;
  for (int kt = 0; kt < K; kt += 64) {
    __syncthreads();
#pragma unroll
    for (int kk = 0; kk < 2; ++kk) {
#pragma unroll
      for (int c = 0; c < 2; ++c) {
        const int chunk = 2 * w + c;
        const bf16_t* sA =
            A + (size_t)(row0 + chunk * 16 + srow) * K + kt + 32 * kk + skoff;
        __builtin_amdgcn_global_load_lds(
            (const __attribute__((address_space(1))) unsigned int*)(uintptr_t)sA,
            (__attribute__((address_space(3))) unsigned int*)(uintptr_t)(&As[kk][chunk * 512]),
            16, 0, 0);
      }
      const bf16_t* sB =
          Bw + (size_t)(col0 + w * 16 + srow) * K + kt + 32 * kk + skoff;
      __builtin_amdgcn_global_load_lds(
          (const __attribute__((address_space(1))) unsigned int*)(uintptr_t)sB,
          (__attribute__((address_space(3))) unsigned int*)(uintptr_t)(&Bs[kk][w * 512]),
          16, 0, 0);
    }
    __syncthreads();
#pragma unroll
    for (int kk = 0; kk < 2; ++kk) {
      bf16x8 af[4], bfv[2];
#pragma unroll
      for (int mi = 0; mi < 4; ++mi) {
        int r = 64 * wm + 16 * mi + rr;
        af[mi] = *(const bf16x8*)(&As[kk][r * 32 + ((kg ^ (r & 3)) << 3)]);
      }
#pragma unroll
      for (int ni = 0; ni < 2; ++ni) {
        int r = 32 * wn + 16 * ni + rr;
        bfv[ni] = *(const bf16x8*)(&Bs[kk][r * 32 + ((kg ^ (r & 3)) << 3)]);
      }
#pragma unroll
      for (int mi = 0; mi < 4; ++mi)
#pragma unroll
        for (int ni = 0; ni < 2; ++ni)
          acc[mi][ni] = __builtin_amdgcn_mfma_f32_16x16x32_bf16(af[mi], bfv[ni],
                                                                acc[mi][ni], 0, 0, 0);
    }
  }
  const int crow = (lane >> 4) * 4, ccol = lane & 15;
  if (QKV && col0 == DIM_ + HD_) {
    // V col-tile -> transposed store vt[d][row]
#pragma unroll
    for (int mi = 0; mi < 4; ++mi)
#pragma unroll
      for (int ni = 0; ni < 2; ++ni) {
        int d = 32 * wn + 16 * ni + ccol;
        size_t rg = (size_t)(row0 + 64 * wm + 16 * mi + crow);
        bf16x4 pk;
#pragma unroll
        for (int r = 0; r < 4; ++r) pk[r] = (bf16_t)acc[mi][ni][r];
        *(bf16x4*)(vt + (size_t)d * NROWS_ + rg) = pk;
      }
  } else if (QKV) {
    // fused RMSNorm + RoPE (col-tile = one full head of 64 dims)
    const float* gam = (col0 < DIM_) ? qg : kgm;
    const float g0 = gam[32 * wn + ccol];
    const float g1 = gam[32 * wn + 16 + ccol];
    const float qs = (col0 < DIM_) ? CT_SCALE : 1.f;
#pragma unroll
    for (int mi = 0; mi < 4; ++mi)
#pragma unroll
      for (int r = 0; r < 4; ++r) {
        float ss = acc[mi][0][r] * acc[mi][0][r] + acc[mi][1][r] * acc[mi][1][r];
        ss += __shfl_xor(ss, 1, 64);
        ss += __shfl_xor(ss, 2, 64);
        ss += __shfl_xor(ss, 4, 64);
        ss += __shfl_xor(ss, 8, 64);
        if (ccol == 0) RowS[64 * wm + 16 * mi + crow + r][wn] = ss;
      }
    __syncthreads();
#pragma unroll
    for (int mi = 0; mi < 4; ++mi)
#pragma unroll
      for (int r = 0; r < 4; ++r) {
        const int row = 64 * wm + 16 * mi + crow + r;
        const int t = (row0 + row) & (T_ - 1);
        const float rms =
            rsqrtf((RowS[row][0] + RowS[row][1]) * (1.f / HD_) + 1e-6f);
#pragma unroll
        for (int ni = 0; ni < 2; ++ni) {
          const int col = 32 * wn + 16 * ni + ccol;
          float val = acc[mi][ni][r] * rms * (ni ? g1 : g0);
          float partner = __shfl_xor(val, 1, 64);
          float c = fc[t * (HD_ / 2) + (col >> 1)];
          float s = fs[t * (HD_ / 2) + (col >> 1)];
          float res = ((ccol & 1) == 0) ? (val * c - partner * s)
                                        : (partner * s + val * c);
          ((bf16_t*)Cv)[(size_t)(row0 + row) * N + col0 + col] = (bf16_t)(res * qs);
        }
      }
  } else {
#pragma unroll
    for (int mi = 0; mi < 4; ++mi)
#pragma unroll
      for (int ni = 0; ni < 2; ++ni)
#pragma unroll
        for (int r = 0; r < 4; ++r) {
          size_t rg = (size_t)(row0 + 64 * wm + 16 * mi + crow + r);
          size_t cg = (size_t)(col0 + 32 * wn + 16 * ni + ccol);
          if (OUTF32) ((float*)Cv)[rg * N + cg] = acc[mi][ni][r];
          else        ((bf16_t*)Cv)[rg * N + cg] = (bf16_t)acc[mi][ni][r];
        }
  }
}

// ---------------- attn part 1: uniform split-K flash units ----------------
// r13 structure + double-buffered K/V staging: STAGE(j+1) -> other buffer is
// issued BEFORE compute(j); ONE barrier per pair-step (was two). LDS 66.5KB
// -> 2 blocks/CU. Softcap poly: C4 term dropped (exponent err <2e-4).
__global__ __launch_bounds__(512, 4) void attn_part(const bf16_t* __restrict__ qkv,
                                                    const bf16_t* __restrict__ vt,
                                                    bf16_t* __restrict__ partO,
                                                    float* __restrict__ partL,
                                                    bf16_t* __restrict__ att) {
  __shared__ __align__(16) char SMEM[65536];
  __shared__ float Lx[4][32];
  __shared__ float Lf[4][32];
  bf16_t* Ks = (bf16_t*)SMEM;            // [2buf][2slice][64*64]
  bf16_t* Vt = (bf16_t*)(SMEM + 32768);  // [2buf][2slice][64*64] transposed [d][t]
  const int tid = threadIdx.x;
  const int w = tid >> 6, lane = tid & 63;
  // ---- decode unit (heavy chunks first) ----
  const int u = NUNITS - 1 - (int)blockIdx.x;
  const int bh = u / UNITS_PER_BH;          // b*8 + head-pair
  const int rem = u - bh * UNITS_PER_BH;
  const int b = bh >> 3, hp = bh & 7;
  int qt = 0;
  while (qt < 31 && cb(qt + 1) <= rem) ++qt;
  const int chunk = rem - cb(qt);
  const int nt = min(8, qt + 1 - chunk * 8);   // tiles in this chunk (1..8)
  const int NP = (nt + 1) >> 1;                // pair-steps
  const int qt0 = qt * 64;
  const int h0 = hp * 2;
  const size_t bT = (size_t)b * T_;
  const int lo = lane & 31, hi = lane >> 5;
  const int hw = w >> 2, qg = (w >> 1) & 1, ks = w & 1, g2 = w >> 1;

  bf16x8 qf[4];
  {
    const bf16_t* qbase =
        qkv + (bT + qt0 + 32 * qg + lo) * NQKV + (h0 + hw) * HD_ + hi * 8;
#pragma unroll
    for (int s = 0; s < 4; ++s) qf[s] = *(const bf16x8*)(qbase + 16 * s);
  }
  const int srow = tid >> 3, scol = (tid & 7) * 8;
  const bf16_t* kp = qkv + (bT + chunk * 512 + srow) * NQKV + DIM_ + scol;
  const bf16_t* vtp = vt + (size_t)srow * NROWS_ + bT + chunk * 512 + scol;
  uint4 kpre0, kpre1, vpre0, vpre1;

#define PREFETCH() do {                                                       \
    kpre0 = *(const uint4*)kp;                                                \
    kpre1 = *(const uint4*)(kp + (size_t)64 * NQKV);                          \
    vpre0 = *(const uint4*)vtp;                                               \
    vpre1 = *(const uint4*)(vtp + 64);                                        \
    kp += (size_t)128 * NQKV;                                                 \
    vtp += 128;                                                               \
  } while (0)
#define STAGE(BUF) do {                                                       \
    *(uint4*)swz(Ks + (BUF) * 8192, srow, scol) = kpre0;                      \
    *(uint4*)swz(Ks + (BUF) * 8192 + 4096, srow, scol) = kpre1;               \
    *(uint4*)swz(Vt + (BUF) * 8192, srow, scol) = vpre0;                      \
    *(uint4*)swz(Vt + (BUF) * 8192 + 4096, srow, scol) = vpre1;               \
  } while (0)

  f32x16 accO0 = {}, accO1 = {};
  float l_ = 0.f;

  PREFETCH();
  STAGE(0);
  if (NP > 1) PREFETCH();
  __syncthreads();

  int cur = 0;
  for (int j = 0; j < NP; ++j) {
    if (j + 1 < NP) {
      STAGE(cur ^ 1);
      if (j + 2 < NP) PREFETCH();
    }
    const int ctl = 2 * j + ks;
    if (ctl < nt) {
      const int ct = chunk * 8 + ctl;   // global 64-key tile index
      bf16_t* KsP = Ks + cur * 8192 + ks * 4096;
      bf16_t* VtP = Vt + cur * 8192 + ks * 4096;
      f32x16 S0 = {}, S1 = {};
      __builtin_amdgcn_s_setprio(1);
#pragma unroll
      for (int s = 0; s < 4; ++s) {
        bf16x8 kf0 = *(const bf16x8*)swz(KsP, lo, 16 * s + hi * 8);
        bf16x8 kf1 = *(const bf16x8*)swz(KsP, 32 + lo, 16 * s + hi * 8);
        S0 = mfma32(kf0, qf[s], S0);
        S1 = mfma32(kf1, qf[s], S1);
      }
      __builtin_amdgcn_s_setprio(0);
      const bool full = (64 * ct + 63 <= qt0 + 32 * qg);
      const int qrel = qt0 + 32 * qg + lo - 64 * ct;
      float psum = 0.f;
#pragma unroll
      for (int kh = 0; kh < 2; ++kh)
#pragma unroll
        for (int r = 0; r < 16; ++r) {
          float t = (kh == 0) ? S0[r] : S1[r];
          float t2 = t * t;
          float pv = exp2f(fmaf(t * t2, C2_, t));
          if (!full) {
            int koff = 32 * kh + (r & 3) + 8 * (r >> 2) + 4 * hi;
            pv = (koff <= qrel) ? pv : 0.f;
          }
          psum += pv;
          if (kh == 0) S0[r] = pv; else S1[r] = pv;
        }
      psum += __shfl_xor(psum, 32, 64);
      l_ += psum;
      __builtin_amdgcn_s_setprio(1);
#pragma unroll
      for (int s = 0; s < 4; ++s) {
        const int base = (s & 1) * 8;
        float p0, p1, p2, p3, p4, p5, p6, p7;
        if (s >> 1) {
          p0 = S1[base + 0]; p1 = S1[base + 1]; p2 = S1[base + 2]; p3 = S1[base + 3];
          p4 = S1[base + 4]; p5 = S1[base + 5]; p6 = S1[base + 6]; p7 = S1[base + 7];
        } else {
          p0 = S0[base + 0]; p1 = S0[base + 1]; p2 = S0[base + 2]; p3 = S0[base + 3];
          p4 = S0[base + 4]; p5 = S0[base + 5]; p6 = S0[base + 6]; p7 = S0[base + 7];
        }
        unsigned a0 = cvt_pk(p0, p1), a1 = cvt_pk(p2, p3);
        unsigned b0 = cvt_pk(p4, p5), b1 = cvt_pk(p6, p7);
        plswap(a0, b0);
        plswap(a1, b1);
        union { unsigned uu[4]; bf16x8 v; } pa;
        pa.uu[0] = a0; pa.uu[1] = a1; pa.uu[2] = b0; pa.uu[3] = b1;
        bf16x8 vf0 = *(const bf16x8*)swz(VtP, lo, 16 * s + hi * 8);
        bf16x8 vf1 = *(const bf16x8*)swz(VtP, 32 + lo, 16 * s + hi * 8);
        accO0 = mfma32(pa.v, vf0, accO0);
        accO1 = mfma32(pa.v, vf1, accO1);
      }
      __builtin_amdgcn_s_setprio(0);
    }
    __syncthreads();
    cur ^= 1;
  }
#undef PREFETCH
#undef STAGE

  // merge kslices in LDS (reuse K/V space); ks=0 writes output/partials
  float* exch = (float*)SMEM;
  float* my = exch + ((size_t)g2 * 64 + lane) * 32;
  if (ks == 1) {
#pragma unroll
    for (int qd = 0; qd < 4; ++qd) {
      int sl = (qd ^ (lane & 7)) * 4;
      f32x4 t0 = {accO0[4*qd], accO0[4*qd+1], accO0[4*qd+2], accO0[4*qd+3]};
      *(f32x4*)(my + sl) = t0;
      int sl2 = ((qd + 4) ^ (lane & 7)) * 4;
      f32x4 t1 = {accO1[4*qd], accO1[4*qd+1], accO1[4*qd+2], accO1[4*qd+3]};
      *(f32x4*)(my + sl2) = t1;
    }
    if (hi == 0) Lx[g2][lo] = l_;
  }
  __syncthreads();
  if (ks == 0) {
#pragma unroll
    for (int qd = 0; qd < 4; ++qd) {
      int sl = (qd ^ (lane & 7)) * 4;
      f32x4 t0 = *(const f32x4*)(my + sl);
      accO0[4*qd] += t0[0]; accO0[4*qd+1] += t0[1];
      accO0[4*qd+2] += t0[2]; accO0[4*qd+3] += t0[3];
      int sl2 = ((qd + 4) ^ (lane & 7)) * 4;
      f32x4 t1 = *(const f32x4*)(my + sl2);
      accO1[4*qd] += t1[0]; accO1[4*qd+1] += t1[1];
      accO1[4*qd+2] += t1[2]; accO1[4*qd+3] += t1[3];
    }
    float l_tot = l_ + Lx[g2][lo];
    if (qt < 8) {
      if (hi == 0) Lf[g2][lo] = l_tot;
#pragma unroll
      for (int rq = 0; rq < 4; ++rq) {
        f32x4 lv = *(const f32x4*)&Lf[g2][8 * rq + 4 * hi];
#pragma unroll
        for (int c = 0; c < 4; ++c) {
          size_t grow = bT + qt0 + 32 * qg + 8 * rq + 4 * hi + c;
          float linv = 1.f / lv[c];
          att[grow * DIM_ + (h0 + hw) * HD_ + lo] =
              (bf16_t)(accO0[4 * rq + c] * linv);
          att[grow * DIM_ + (h0 + hw) * HD_ + 32 + lo] =
              (bf16_t)(accO1[4 * rq + c] * linv);
        }
      }
    } else {
      bf16_t* po = partO + ((size_t)u * 2 + hw) * 4096;
#pragma unroll
      for (int rq = 0; rq < 4; ++rq)
#pragma unroll
        for (int c = 0; c < 4; ++c) {
          int q = 32 * qg + 8 * rq + 4 * hi + c;
          po[q * 64 + lo] = (bf16_t)accO0[4 * rq + c];
          po[q * 64 + 32 + lo] = (bf16_t)accO1[4 * rq + c];
        }
      if (hi == 0) partL[((size_t)u * 2 + hw) * 64 + 32 * qg + lo] = l_tot;
    }
  }
}

// ---------------- attn part 2: merge partials (qt >= 8 only) ----------------
__global__ __launch_bounds__(256) void attn_reduce(const bf16_t* __restrict__ partO,
                                                   const float* __restrict__ partL,
                                                   bf16_t* __restrict__ att) {
  const int qt = blockIdx.x + 8, h = blockIdx.y, b = blockIdx.z;
  const int nch = (qt + 8) >> 3;
  const size_t ubase = (size_t)(b * 8 + (h >> 1)) * UNITS_PER_BH + cb(qt);
  const int hw = h & 1;
  const int tid = threadIdx.x;
  const int q = tid >> 2, dblk = (tid & 3) * 16;
  f32x4 o[4] = {};
  float l = 0.f;
  for (int c = 0; c < nch; ++c) {
    const bf16_t* po = partO + ((ubase + c) * 2 + hw) * 4096 + q * 64 + dblk;
    bf16x8 v0 = *(const bf16x8*)po;
    bf16x8 v1 = *(const bf16x8*)(po + 8);
#pragma unroll
    for (int i = 0; i < 4; ++i) o[0][i] += (float)v0[i];
#pragma unroll
    for (int i = 0; i < 4; ++i) o[1][i] += (float)v0[4 + i];
#pragma unroll
    for (int i = 0; i < 4; ++i) o[2][i] += (float)v1[i];
#pragma unroll
    for (int i = 0; i < 4; ++i) o[3][i] += (float)v1[4 + i];
    l += partL[((ubase + c) * 2 + hw) * 64 + q];
  }
  const float linv = 1.f / l;
  bf16_t* dst = att + ((size_t)(b * T_ + qt * 64 + q)) * DIM_ + h * HD_ + dblk;
  bf16x8 r0, r1;
#pragma unroll
  for (int i = 0; i < 4; ++i) { r0[i] = (bf16_t)(o[0][i] * linv);
                                r0[4+i] = (bf16_t)(o[1][i] * linv);
                                r1[i] = (bf16_t)(o[2][i] * linv);
                                r1[4+i] = (bf16_t)(o[3][i] * linv); }
  *(bf16x8*)dst = r0;
  *(bf16x8*)(dst + 8) = r1;
}

extern "C" void kernel_launch(void* const* d_in, const int* in_sizes, int n_in,
                              void* d_out, int out_size, void* d_ws, size_t ws_size,
                              hipStream_t stream) {
  const float* x   = (const float*)d_in[0];
  const float* wq  = (const float*)d_in[1];
  const float* wk  = (const float*)d_in[2];
  const float* wv  = (const float*)d_in[3];
  const float* wo  = (const float*)d_in[4];
  const float* qg  = (const float*)d_in[5];
  const float* kgm = (const float*)d_in[6];
  const float* fc  = (const float*)d_in[7];
  const float* fs  = (const float*)d_in[8];
  float* out = (float*)d_out;

  bf16_t* xb    = (bf16_t*)d_ws;
  bf16_t* wqkvb = xb + (size_t)NROWS_ * DIM_;
  bf16_t* wob   = wqkvb + (size_t)NQKV * DIM_;
  bf16_t* qkvo  = wob + (size_t)DIM_ * DIM_;
  bf16_t* attb  = qkvo + (size_t)NROWS_ * NQKV;
  bf16_t* partO = attb + (size_t)NROWS_ * DIM_;                 // NUNITS*2*4096 bf16
  float*  partL = (float*)(partO + (size_t)NUNITS * 2 * 4096);  // NUNITS*2*64 f32
  bf16_t* vtb   = (bf16_t*)(partL + (size_t)NUNITS * 2 * 64);   // HD_ x NROWS_ bf16

  cvt_all<<<(C_S4 + 255) / 256, 256, 0, stream>>>(x, wq, wk, wv, wo, xb, wqkvb, wob);
  gemm_bt<0, 1><<<dim3(NROWS_ / 128, NQKV / 64), 256, 0, stream>>>(
      xb, wqkvb, qkvo, vtb, qg, kgm, fc, fs, NQKV, DIM_);
  attn_part<<<NUNITS, 512, 0, stream>>>(qkvo, vtb, partO, partL, attb);
  attn_reduce<<<dim3(24, H_, B_), 256, 0, stream>>>(partO, partL, attb);
  gemm_bt<1, 0><<<dim3(NROWS_ / 128, DIM_ / 64), 256, 0, stream>>>(
      attb, wob, out, nullptr, nullptr, nullptr, nullptr, nullptr, DIM_, DIM_);
}

// Round 16
// 108.790 us; speedup vs baseline: 1.0426x; 1.0136x over previous
//
#include <hip/hip_runtime.h>
#include <hip/hip_bf16.h>
#include <stdint.h>
#include <math.h>

#define B_ 2
#define T_ 2048
#define DIM_ 1024
#define H_ 16
#define HD_ 64
#define NROWS_ (B_*T_)
#define NQKV 1152
#define UNITS_PER_BH 80   // sum_{qt=0}^{31} ceil((qt+1)/8)
#define NUNITS (16 * UNITS_PER_BH)
// Q pre-scale folded into projection epilogue: scores come out as t = s*0.125*log2e
#define CT_SCALE 0.18033688f
// softcap in t-domain: 50*tanh(s/400)*log2e ~= t + C2*t^3 (|t|<=11.6; C4 term <2e-4)
#define C2_ (-6.40603e-5f)

typedef __bf16 bf16_t;
typedef __attribute__((ext_vector_type(8))) __bf16 bf16x8;
typedef __attribute__((ext_vector_type(4))) __bf16 bf16x4;
typedef __attribute__((ext_vector_type(4))) float f32x4;
typedef __attribute__((ext_vector_type(16))) float f32x16;

// cumulative chunk count: cb(qt) = sum_{m=1}^{qt} ceil(m/8)
__device__ __forceinline__ int cb(int q) {
  int a = q >> 3, r = q & 7;
  return 4 * a * (a + 1) + r * (a + 1);
}

// Swizzled LDS byte address for [rows][64] bf16 tiles (128B rows):
// byte = row*128 + ((col*2) ^ ((row&7)<<4)).
__device__ __forceinline__ bf16_t* swz(bf16_t* base, int row, int col) {
  return (bf16_t*)((char*)base + (row << 7) + (((col << 1) ^ ((row & 7) << 4))));
}

__device__ __forceinline__ f32x16 mfma32(bf16x8 a, bf16x8 b, f32x16 c) {
  return __builtin_amdgcn_mfma_f32_32x32x16_bf16(a, b, c, 0, 0, 0);
}

__device__ __forceinline__ unsigned cvt_pk(float lo, float hi) {
  unsigned r;
  asm("v_cvt_pk_bf16_f32 %0, %1, %2" : "=v"(r) : "v"(lo), "v"(hi));
  return r;
}
__device__ __forceinline__ void plswap(unsigned& x, unsigned& y) {
  asm volatile("v_permlane32_swap_b32 %0, %1" : "+v"(x), "+v"(y));
}

#define GLOAD(SRC, DST)                                                        \
  __builtin_amdgcn_global_load_lds(                                            \
      (const __attribute__((address_space(1))) unsigned int*)(uintptr_t)(SRC), \
      (__attribute__((address_space(3))) unsigned int*)(uintptr_t)(DST), 16, 0, 0)

// ---------------- single fused f32 -> bf16 conversion ----------------
#define C_S0 (NROWS_*DIM_/8)
#define C_S1 (C_S0 + DIM_*DIM_/8)
#define C_S2 (C_S1 + HD_*DIM_/8)
#define C_S3 (C_S2 + HD_*DIM_/8)
#define C_S4 (C_S3 + DIM_*DIM_/8)
__global__ __launch_bounds__(256) void cvt_all(
    const float* __restrict__ x, const float* __restrict__ wq,
    const float* __restrict__ wk, const float* __restrict__ wv,
    const float* __restrict__ wo, bf16_t* __restrict__ xb,
    bf16_t* __restrict__ wqkvb, bf16_t* __restrict__ wob) {
  int i = blockIdx.x * 256 + threadIdx.x;
  if (i >= C_S4) return;
  const float* src; bf16_t* dst; int j;
  if (i < C_S0)      { src = x;  dst = xb; j = i; }
  else if (i < C_S1) { src = wq; dst = wqkvb; j = i - C_S0; }
  else if (i < C_S2) { src = wk; dst = wqkvb + (size_t)DIM_ * DIM_; j = i - C_S1; }
  else if (i < C_S3) { src = wv; dst = wqkvb + (size_t)(DIM_ + HD_) * DIM_; j = i - C_S2; }
  else               { src = wo; dst = wob; j = i - C_S3; }
  float4 a = ((const float4*)src)[2 * (size_t)j];
  float4 b = ((const float4*)src)[2 * (size_t)j + 1];
  bf16x8 o;
  o[0] = (bf16_t)a.x; o[1] = (bf16_t)a.y; o[2] = (bf16_t)a.z; o[3] = (bf16_t)a.w;
  o[4] = (bf16_t)b.x; o[5] = (bf16_t)b.y; o[6] = (bf16_t)b.z; o[7] = (bf16_t)b.w;
  *(bf16x8*)(dst + 8 * (size_t)j) = o;
}

// ---------------- bf16 MFMA GEMM (r13-proven), C[m][n] = sum_k A[m][k]*Bw[n][k] ----------------
// 128x64 tile, BK=64, 256 threads. QKV mode: col-tile = one full head ->
//   q/k heads: fused RMSNorm + RoPE epilogue (q additionally * CT_SCALE)
//   v head: written TRANSPOSED to vt[d][row].
template<int OUTF32, int QKV>
__global__ __launch_bounds__(256) void gemm_bt(const bf16_t* __restrict__ A,
    const bf16_t* __restrict__ Bw, void* __restrict__ Cv,
    bf16_t* __restrict__ vt, const float* __restrict__ qg,
    const float* __restrict__ kgm, const float* __restrict__ fc,
    const float* __restrict__ fs, int N, int K) {
  __shared__ bf16_t As[2][128 * 32];
  __shared__ bf16_t Bs[2][64 * 32];
  __shared__ float RowS[128][2];
  const int tid = threadIdx.x;
  const int w = tid >> 6, lane = tid & 63;
  const int row0 = blockIdx.x * 128, col0 = blockIdx.y * 64;
  const int wm = w >> 1, wn = w & 1;
  const int rr = lane & 15, kg = lane >> 4;
  f32x4 acc[4][2];
#pragma unroll
  for (int i = 0; i < 4; ++i)
#pragma unroll
    for (int j = 0; j < 2; ++j) acc[i][j] = (f32x4){0.f, 0.f, 0.f, 0.f};
  const int srow = lane >> 2;
  const int skoff = ((lane & 3) ^ (srow & 3)) << 3;
  for (int kt = 0; kt < K; kt += 64) {
    __syncthreads();
#pragma unroll
    for (int kk = 0; kk < 2; ++kk) {
#pragma unroll
      for (int c = 0; c < 2; ++c) {
        const int chunk = 2 * w + c;
        const bf16_t* sA =
            A + (size_t)(row0 + chunk * 16 + srow) * K + kt + 32 * kk + skoff;
        GLOAD(sA, &As[kk][chunk * 512]);
      }
      const bf16_t* sB =
          Bw + (size_t)(col0 + w * 16 + srow) * K + kt + 32 * kk + skoff;
      GLOAD(sB, &Bs[kk][w * 512]);
    }
    __syncthreads();
#pragma unroll
    for (int kk = 0; kk < 2; ++kk) {
      bf16x8 af[4], bfv[2];
#pragma unroll
      for (int mi = 0; mi < 4; ++mi) {
        int r = 64 * wm + 16 * mi + rr;
        af[mi] = *(const bf16x8*)(&As[kk][r * 32 + ((kg ^ (r & 3)) << 3)]);
      }
#pragma unroll
      for (int ni = 0; ni < 2; ++ni) {
        int r = 32 * wn + 16 * ni + rr;
        bfv[ni] = *(const bf16x8*)(&Bs[kk][r * 32 + ((kg ^ (r & 3)) << 3)]);
      }
#pragma unroll
      for (int mi = 0; mi < 4; ++mi)
#pragma unroll
        for (int ni = 0; ni < 2; ++ni)
          acc[mi][ni] = __builtin_amdgcn_mfma_f32_16x16x32_bf16(af[mi], bfv[ni],
                                                                acc[mi][ni], 0, 0, 0);
    }
  }
  const int crow = (lane >> 4) * 4, ccol = lane & 15;
  if (QKV && col0 == DIM_ + HD_) {
    // V col-tile -> transposed store vt[d][row]
#pragma unroll
    for (int mi = 0; mi < 4; ++mi)
#pragma unroll
      for (int ni = 0; ni < 2; ++ni) {
        int d = 32 * wn + 16 * ni + ccol;
        size_t rg = (size_t)(row0 + 64 * wm + 16 * mi + crow);
        bf16x4 pk;
#pragma unroll
        for (int r = 0; r < 4; ++r) pk[r] = (bf16_t)acc[mi][ni][r];
        *(bf16x4*)(vt + (size_t)d * NROWS_ + rg) = pk;
      }
  } else if (QKV) {
    // fused RMSNorm + RoPE (col-tile = one full head of 64 dims)
    const float* gam = (col0 < DIM_) ? qg : kgm;
    const float g0 = gam[32 * wn + ccol];
    const float g1 = gam[32 * wn + 16 + ccol];
    const float qs = (col0 < DIM_) ? CT_SCALE : 1.f;
#pragma unroll
    for (int mi = 0; mi < 4; ++mi)
#pragma unroll
      for (int r = 0; r < 4; ++r) {
        float ss = acc[mi][0][r] * acc[mi][0][r] + acc[mi][1][r] * acc[mi][1][r];
        ss += __shfl_xor(ss, 1, 64);
        ss += __shfl_xor(ss, 2, 64);
        ss += __shfl_xor(ss, 4, 64);
        ss += __shfl_xor(ss, 8, 64);
        if (ccol == 0) RowS[64 * wm + 16 * mi + crow + r][wn] = ss;
      }
    __syncthreads();
#pragma unroll
    for (int mi = 0; mi < 4; ++mi)
#pragma unroll
      for (int r = 0; r < 4; ++r) {
        const int row = 64 * wm + 16 * mi + crow + r;
        const int t = (row0 + row) & (T_ - 1);
        const float rms =
            rsqrtf((RowS[row][0] + RowS[row][1]) * (1.f / HD_) + 1e-6f);
#pragma unroll
        for (int ni = 0; ni < 2; ++ni) {
          const int col = 32 * wn + 16 * ni + ccol;
          float val = acc[mi][ni][r] * rms * (ni ? g1 : g0);
          float partner = __shfl_xor(val, 1, 64);
          float c = fc[t * (HD_ / 2) + (col >> 1)];
          float s = fs[t * (HD_ / 2) + (col >> 1)];
          float res = ((ccol & 1) == 0) ? (val * c - partner * s)
                                        : (partner * s + val * c);
          ((bf16_t*)Cv)[(size_t)(row0 + row) * N + col0 + col] = (bf16_t)(res * qs);
        }
      }
  } else {
#pragma unroll
    for (int mi = 0; mi < 4; ++mi)
#pragma unroll
      for (int ni = 0; ni < 2; ++ni)
#pragma unroll
        for (int r = 0; r < 4; ++r) {
          size_t rg = (size_t)(row0 + 64 * wm + 16 * mi + crow + r);
          size_t cg = (size_t)(col0 + 32 * wn + 16 * ni + ccol);
          if (OUTF32) ((float*)Cv)[rg * N + cg] = acc[mi][ni][r];
          else        ((bf16_t*)Cv)[rg * N + cg] = (bf16_t)acc[mi][ni][r];
        }
  }
}

// ---------------- attn part 1: uniform split-K flash units ----------------
// r15 structure (double-buffered K/V, 1 barrier/step). Staging now via
// global_load_lds with PRE-SWIZZLED GLOBAL SOURCE (rule #21: linear LDS dest
// + inverse-swz source + swz on read; XOR swizzle is an involution). Deletes
// the 4 ds_writes + 16 prefetch VGPRs + addr math per step; loads for step
// j+1 fly during compute(j) and drain at the barrier.
__global__ __launch_bounds__(512, 4) void attn_part(const bf16_t* __restrict__ qkv,
                                                    const bf16_t* __restrict__ vt,
                                                    bf16_t* __restrict__ partO,
                                                    float* __restrict__ partL,
                                                    bf16_t* __restrict__ att) {
  __shared__ __align__(16) char SMEM[65536];
  __shared__ float Lx[4][32];
  __shared__ float Lf[4][32];
  bf16_t* Ks = (bf16_t*)SMEM;            // [2buf][2slice][64*64]
  bf16_t* Vt = (bf16_t*)(SMEM + 32768);  // [2buf][2slice][64*64] transposed [d][t]
  const int tid = threadIdx.x;
  const int w = tid >> 6, lane = tid & 63;
  // ---- decode unit (heavy chunks first) ----
  const int u = NUNITS - 1 - (int)blockIdx.x;
  const int bh = u / UNITS_PER_BH;          // b*8 + head-pair
  const int rem = u - bh * UNITS_PER_BH;
  const int b = bh >> 3, hp = bh & 7;
  int qt = 0;
  while (qt < 31 && cb(qt + 1) <= rem) ++qt;
  const int chunk = rem - cb(qt);
  const int nt = min(8, qt + 1 - chunk * 8);   // tiles in this chunk (1..8)
  const int NP = (nt + 1) >> 1;                // pair-steps
  const int qt0 = qt * 64;
  const int h0 = hp * 2;
  const size_t bT = (size_t)b * T_;
  const int lo = lane & 31, hi = lane >> 5;
  const int hw = w >> 2, qg = (w >> 1) & 1, ks = w & 1, g2 = w >> 1;

  bf16x8 qf[4];
  {
    const bf16_t* qbase =
        qkv + (bT + qt0 + 32 * qg + lo) * NQKV + (h0 + hw) * HD_ + hi * 8;
#pragma unroll
    for (int s = 0; s < 4; ++s) qf[s] = *(const bf16x8*)(qbase + 16 * s);
  }
  // staging: thread (srow, slot) feeds linear LDS byte tid*16; the content
  // belonging there is column scol2 = ((slot*16) ^ ((srow&7)<<4))/2 elements.
  const int srow = tid >> 3;
  const int scol2 = (((tid & 7) << 4) ^ ((srow & 7) << 4)) >> 1;
  const bf16_t* kp = qkv + (bT + chunk * 512 + srow) * NQKV + DIM_ + scol2;
  const bf16_t* vtp = vt + (size_t)srow * NROWS_ + bT + chunk * 512 + scol2;
  // wave-uniform LDS bases (each wave's 64 lanes x 16B = 1KB = 512 elems)
  const int woff = w * 512;

#define STAGE(BUF) do {                                                       \
    GLOAD(kp, Ks + (BUF) * 8192 + woff);                                      \
    GLOAD(kp + (size_t)64 * NQKV, Ks + (BUF) * 8192 + 4096 + woff);           \
    GLOAD(vtp, Vt + (BUF) * 8192 + woff);                                     \
    GLOAD(vtp + 64, Vt + (BUF) * 8192 + 4096 + woff);                         \
    kp += (size_t)128 * NQKV;                                                 \
    vtp += 128;                                                               \
  } while (0)

  f32x16 accO0 = {}, accO1 = {};
  float l_ = 0.f;

  STAGE(0);
  __syncthreads();

  int cur = 0;
  for (int j = 0; j < NP; ++j) {
    if (j + 1 < NP) STAGE(cur ^ 1);
    const int ctl = 2 * j + ks;
    if (ctl < nt) {
      const int ct = chunk * 8 + ctl;   // global 64-key tile index
      bf16_t* KsP = Ks + cur * 8192 + ks * 4096;
      bf16_t* VtP = Vt + cur * 8192 + ks * 4096;
      f32x16 S0 = {}, S1 = {};
      __builtin_amdgcn_s_setprio(1);
#pragma unroll
      for (int s = 0; s < 4; ++s) {
        bf16x8 kf0 = *(const bf16x8*)swz(KsP, lo, 16 * s + hi * 8);
        bf16x8 kf1 = *(const bf16x8*)swz(KsP, 32 + lo, 16 * s + hi * 8);
        S0 = mfma32(kf0, qf[s], S0);
        S1 = mfma32(kf1, qf[s], S1);
      }
      __builtin_amdgcn_s_setprio(0);
      const bool full = (64 * ct + 63 <= qt0 + 32 * qg);
      const int qrel = qt0 + 32 * qg + lo - 64 * ct;
      float psum = 0.f;
#pragma unroll
      for (int kh = 0; kh < 2; ++kh)
#pragma unroll
        for (int r = 0; r < 16; ++r) {
          float t = (kh == 0) ? S0[r] : S1[r];
          float t2 = t * t;
          float pv = exp2f(fmaf(t * t2, C2_, t));
          if (!full) {
            int koff = 32 * kh + (r & 3) + 8 * (r >> 2) + 4 * hi;
            pv = (koff <= qrel) ? pv : 0.f;
          }
          psum += pv;
          if (kh == 0) S0[r] = pv; else S1[r] = pv;
        }
      psum += __shfl_xor(psum, 32, 64);
      l_ += psum;
      __builtin_amdgcn_s_setprio(1);
#pragma unroll
      for (int s = 0; s < 4; ++s) {
        const int base = (s & 1) * 8;
        float p0, p1, p2, p3, p4, p5, p6, p7;
        if (s >> 1) {
          p0 = S1[base + 0]; p1 = S1[base + 1]; p2 = S1[base + 2]; p3 = S1[base + 3];
          p4 = S1[base + 4]; p5 = S1[base + 5]; p6 = S1[base + 6]; p7 = S1[base + 7];
        } else {
          p0 = S0[base + 0]; p1 = S0[base + 1]; p2 = S0[base + 2]; p3 = S0[base + 3];
          p4 = S0[base + 4]; p5 = S0[base + 5]; p6 = S0[base + 6]; p7 = S0[base + 7];
        }
        unsigned a0 = cvt_pk(p0, p1), a1 = cvt_pk(p2, p3);
        unsigned b0 = cvt_pk(p4, p5), b1 = cvt_pk(p6, p7);
        plswap(a0, b0);
        plswap(a1, b1);
        union { unsigned uu[4]; bf16x8 v; } pa;
        pa.uu[0] = a0; pa.uu[1] = a1; pa.uu[2] = b0; pa.uu[3] = b1;
        bf16x8 vf0 = *(const bf16x8*)swz(VtP, lo, 16 * s + hi * 8);
        bf16x8 vf1 = *(const bf16x8*)swz(VtP, 32 + lo, 16 * s + hi * 8);
        accO0 = mfma32(pa.v, vf0, accO0);
        accO1 = mfma32(pa.v, vf1, accO1);
      }
      __builtin_amdgcn_s_setprio(0);
    }
    __syncthreads();
    cur ^= 1;
  }
#undef STAGE

  // merge kslices in LDS (reuse K/V space); ks=0 writes output/partials
  float* exch = (float*)SMEM;
  float* my = exch + ((size_t)g2 * 64 + lane) * 32;
  if (ks == 1) {
#pragma unroll
    for (int qd = 0; qd < 4; ++qd) {
      int sl = (qd ^ (lane & 7)) * 4;
      f32x4 t0 = {accO0[4*qd], accO0[4*qd+1], accO0[4*qd+2], accO0[4*qd+3]};
      *(f32x4*)(my + sl) = t0;
      int sl2 = ((qd + 4) ^ (lane & 7)) * 4;
      f32x4 t1 = {accO1[4*qd], accO1[4*qd+1], accO1[4*qd+2], accO1[4*qd+3]};
      *(f32x4*)(my + sl2) = t1;
    }
    if (hi == 0) Lx[g2][lo] = l_;
  }
  __syncthreads();
  if (ks == 0) {
#pragma unroll
    for (int qd = 0; qd < 4; ++qd) {
      int sl = (qd ^ (lane & 7)) * 4;
      f32x4 t0 = *(const f32x4*)(my + sl);
      accO0[4*qd] += t0[0]; accO0[4*qd+1] += t0[1];
      accO0[4*qd+2] += t0[2]; accO0[4*qd+3] += t0[3];
      int sl2 = ((qd + 4) ^ (lane & 7)) * 4;
      f32x4 t1 = *(const f32x4*)(my + sl2);
      accO1[4*qd] += t1[0]; accO1[4*qd+1] += t1[1];
      accO1[4*qd+2] += t1[2]; accO1[4*qd+3] += t1[3];
    }
    float l_tot = l_ + Lx[g2][lo];
    if (qt < 8) {
      if (hi == 0) Lf[g2][lo] = l_tot;
#pragma unroll
      for (int rq = 0; rq < 4; ++rq) {
        f32x4 lv = *(const f32x4*)&Lf[g2][8 * rq + 4 * hi];
#pragma unroll
        for (int c = 0; c < 4; ++c) {
          size_t grow = bT + qt0 + 32 * qg + 8 * rq + 4 * hi + c;
          float linv = 1.f / lv[c];
          att[grow * DIM_ + (h0 + hw) * HD_ + lo] =
              (bf16_t)(accO0[4 * rq + c] * linv);
          att[grow * DIM_ + (h0 + hw) * HD_ + 32 + lo] =
              (bf16_t)(accO1[4 * rq + c] * linv);
        }
      }
    } else {
      bf16_t* po = partO + ((size_t)u * 2 + hw) * 4096;
#pragma unroll
      for (int rq = 0; rq < 4; ++rq)
#pragma unroll
        for (int c = 0; c < 4; ++c) {
          int q = 32 * qg + 8 * rq + 4 * hi + c;
          po[q * 64 + lo] = (bf16_t)accO0[4 * rq + c];
          po[q * 64 + 32 + lo] = (bf16_t)accO1[4 * rq + c];
        }
      if (hi == 0) partL[((size_t)u * 2 + hw) * 64 + 32 * qg + lo] = l_tot;
    }
  }
}

// ---------------- attn part 2: merge partials (qt >= 8 only) ----------------
__global__ __launch_bounds__(256) void attn_reduce(const bf16_t* __restrict__ partO,
                                                   const float* __restrict__ partL,
                                                   bf16_t* __restrict__ att) {
  const int qt = blockIdx.x + 8, h = blockIdx.y, b = blockIdx.z;
  const int nch = (qt + 8) >> 3;
  const size_t ubase = (size_t)(b * 8 + (h >> 1)) * UNITS_PER_BH + cb(qt);
  const int hw = h & 1;
  const int tid = threadIdx.x;
  const int q = tid >> 2, dblk = (tid & 3) * 16;
  f32x4 o[4] = {};
  float l = 0.f;
  for (int c = 0; c < nch; ++c) {
    const bf16_t* po = partO + ((ubase + c) * 2 + hw) * 4096 + q * 64 + dblk;
    bf16x8 v0 = *(const bf16x8*)po;
    bf16x8 v1 = *(const bf16x8*)(po + 8);
#pragma unroll
    for (int i = 0; i < 4; ++i) o[0][i] += (float)v0[i];
#pragma unroll
    for (int i = 0; i < 4; ++i) o[1][i] += (float)v0[4 + i];
#pragma unroll
    for (int i = 0; i < 4; ++i) o[2][i] += (float)v1[i];
#pragma unroll
    for (int i = 0; i < 4; ++i) o[3][i] += (float)v1[4 + i];
    l += partL[((ubase + c) * 2 + hw) * 64 + q];
  }
  const float linv = 1.f / l;
  bf16_t* dst = att + ((size_t)(b * T_ + qt * 64 + q)) * DIM_ + h * HD_ + dblk;
  bf16x8 r0, r1;
#pragma unroll
  for (int i = 0; i < 4; ++i) { r0[i] = (bf16_t)(o[0][i] * linv);
                                r0[4+i] = (bf16_t)(o[1][i] * linv);
                                r1[i] = (bf16_t)(o[2][i] * linv);
                                r1[4+i] = (bf16_t)(o[3][i] * linv); }
  *(bf16x8*)dst = r0;
  *(bf16x8*)(dst + 8) = r1;
}

extern "C" void kernel_launch(void* const* d_in, const int* in_sizes, int n_in,
                              void* d_out, int out_size, void* d_ws, size_t ws_size,
                              hipStream_t stream) {
  const float* x   = (const float*)d_in[0];
  const float* wq  = (const float*)d_in[1];
  const float* wk  = (const float*)d_in[2];
  const float* wv  = (const float*)d_in[3];
  const float* wo  = (const float*)d_in[4];
  const float* qg  = (const float*)d_in[5];
  const float* kgm = (const float*)d_in[6];
  const float* fc  = (const float*)d_in[7];
  const float* fs  = (const float*)d_in[8];
  float* out = (float*)d_out;

  bf16_t* xb    = (bf16_t*)d_ws;
  bf16_t* wqkvb = xb + (size_t)NROWS_ * DIM_;
  bf16_t* wob   = wqkvb + (size_t)NQKV * DIM_;
  bf16_t* qkvo  = wob + (size_t)DIM_ * DIM_;
  bf16_t* attb  = qkvo + (size_t)NROWS_ * NQKV;
  bf16_t* partO = attb + (size_t)NROWS_ * DIM_;                 // NUNITS*2*4096 bf16
  float*  partL = (float*)(partO + (size_t)NUNITS * 2 * 4096);  // NUNITS*2*64 f32
  bf16_t* vtb   = (bf16_t*)(partL + (size_t)NUNITS * 2 * 64);   // HD_ x NROWS_ bf16

  cvt_all<<<(C_S4 + 255) / 256, 256, 0, stream>>>(x, wq, wk, wv, wo, xb, wqkvb, wob);
  gemm_bt<0, 1><<<dim3(NROWS_ / 128, NQKV / 64), 256, 0, stream>>>(
      xb, wqkvb, qkvo, vtb, qg, kgm, fc, fs, NQKV, DIM_);
  attn_part<<<NUNITS, 512, 0, stream>>>(qkvo, vtb, partO, partL, attb);
  attn_reduce<<<dim3(24, H_, B_), 256, 0, stream>>>(partO, partL, attb);
  gemm_bt<1, 0><<<dim3(NROWS_ / 128, DIM_ / 64), 256, 0, stream>>>(
      attb, wob, out, nullptr, nullptr, nullptr, nullptr, nullptr, DIM_, DIM_);
}